// Round 3
// baseline (1123.524 us; speedup 1.0000x reference)
//
#include <hip/hip_runtime.h>
#include <hip/hip_bf16.h>

// Problem constants (fixed by the reference)
#define BATCH 8
#define NPTS  4096      // N
#define CCH   128       // C
#define KNN_K 16        // K

typedef __attribute__((ext_vector_type(8))) short  bf16x8;  // 8 bf16 = 4 VGPRs
typedef __attribute__((ext_vector_type(4))) float  f32x4;   // MFMA acc

// ---------------------------------------------------------------------------
// ws layout (bytes):
//   [0)          xTb   : B*N*C bf16      = 8,388,608
//   [8388608)    Wb    : C*C  bf16       =    32,768
//   [8421376)    scale : C fp32          =       512
//   [8421888)    bias  : C fp32          =       512
//   [8422400)    knn   : B*N*K u16       = 1,048,576
//   [9470976)    ptss  : B*N float4(x,y,z,idx) sorted by x = 524,288
// total 9,995,264 (same footprint as round 2)
// ---------------------------------------------------------------------------

static __device__ __forceinline__ short f2bf(float v) {
    __hip_bfloat16 h = __float2bfloat16(v);   // RNE
    return __builtin_bit_cast(short, h);
}

// LDS-tiled transpose: x [B,C,N] fp32 -> xTb [B,N,C] bf16.
__global__ __launch_bounds__(256) void transpose_kernel(
    const float* __restrict__ x, short* __restrict__ xTb)
{
    __shared__ short tile[64 * 66];
    const int tid = threadIdx.x;
    const int b   = blockIdx.x >> 7;         // 8 batches
    const int rem = blockIdx.x & 127;
    const int nt  = rem >> 1;                // 64 n-tiles of 64
    const int ct  = rem & 1;                 // 2 c-tiles of 64

    #pragma unroll
    for (int it = 0; it < 16; ++it) {
        const int idx = it * 256 + tid;
        const int cc  = idx >> 6;
        const int nn  = idx & 63;
        const float v = x[(size_t)(b * CCH + ct * 64 + cc) * NPTS + nt * 64 + nn];
        tile[cc * 66 + nn] = f2bf(v);
    }
    __syncthreads();
    #pragma unroll
    for (int it = 0; it < 16; ++it) {
        const int idx = it * 256 + tid;
        const int nn  = idx >> 6;
        const int cc  = idx & 63;
        xTb[(size_t)(b * NPTS + nt * 64 + nn) * CCH + ct * 64 + cc] = tile[cc * 66 + nn];
    }
}

// Small prep: W -> bf16; fold BN affine
__global__ __launch_bounds__(256) void small_prep_kernel(
    const float* __restrict__ W,
    const float* __restrict__ gamma, const float* __restrict__ beta,
    const float* __restrict__ rmean, const float* __restrict__ rvar,
    short* __restrict__ Wb, float* __restrict__ scale, float* __restrict__ bias)
{
    const int t = blockIdx.x * 256 + threadIdx.x;   // grid covers C*C = 16384
    Wb[t] = f2bf(W[t]);
    if (t < CCH) {
        const float s = gamma[t] / sqrtf(rvar[t] + 1e-5f);
        scale[t] = s;
        bias[t]  = beta[t] - rmean[t] * s;
    }
}

// Per-batch bitonic sort of 4096 points by x-coordinate.
// key = sortable(x)<<32 | original_idx. Output ptss[pos] = (x,y,z, idx_bits).
__global__ __launch_bounds__(512) void sort_kernel(
    const float* __restrict__ xyz, float4* __restrict__ ptss)
{
    __shared__ unsigned long long key[NPTS];
    const int b   = blockIdx.x;
    const int tid = threadIdx.x;
    const float* xb = xyz + (size_t)b * NPTS * 3;

    for (int i = tid; i < NPTS; i += 512) {
        const unsigned ub = __float_as_uint(xb[3 * i]);
        const unsigned sx = (ub & 0x80000000u) ? ~ub : (ub | 0x80000000u);
        key[i] = ((unsigned long long)sx << 32) | (unsigned)i;
    }
    __syncthreads();
    for (int k = 2; k <= NPTS; k <<= 1) {
        for (int j = k >> 1; j > 0; j >>= 1) {
            for (int t = tid; t < NPTS / 2; t += 512) {
                const int i = 2 * t - (t & (j - 1));   // i has bit j clear
                const int l = i | j;
                const unsigned long long a = key[i], c = key[l];
                const bool up = ((i & k) == 0);
                if ((a > c) == up) { key[i] = c; key[l] = a; }
            }
            __syncthreads();
        }
    }
    for (int i = tid; i < NPTS; i += 512) {
        const int oi = (int)(unsigned)(key[i] & 0xFFFFFFFFu);
        ptss[(b << 12) + i] = make_float4(xb[3 * oi], xb[3 * oi + 1], xb[3 * oi + 2],
                                          __uint_as_float((unsigned)oi));
    }
}

// Lexicographic (d, j) sorted-ascending top-16 insert (order-independent,
// preserves reference lowest-index tie-break on exact fp ties).
__device__ __forceinline__ void insert16x(float bd[16], int bi[16], float d, int j) {
    bool lt[16];
    #pragma unroll
    for (int t = 0; t < 16; ++t) lt[t] = (d < bd[t]) || (d == bd[t] && j < bi[t]);
    #pragma unroll
    for (int t = 15; t >= 1; --t) {
        bd[t] = lt[t] ? (lt[t - 1] ? bd[t - 1] : d) : bd[t];
        bi[t] = lt[t] ? (lt[t - 1] ? bi[t - 1] : j) : bi[t];
    }
    if (lt[0]) { bd[0] = d; bi[0] = j; }
}

// Sorted-sweep KNN. 4 lanes per query (substreams: left-even, left-odd,
// right-odd, right-even; each monotone in |rank distance|). Expanding scan
// with (dx)^2 pruning against tau = current 16th-best (+fp margin).
// No LDS: final merge is a 2-round shuffle butterfly.
__global__ __launch_bounds__(256) void knn_kernel(
    const float4* __restrict__ ptss, unsigned short* __restrict__ knn)
{
    const int lane = threadIdx.x & 63;
    const int w    = threadIdx.x >> 6;
    const int qw   = lane & 15;              // query within wave
    const int sub  = lane >> 4;              // substream 0..3
    const int b    = blockIdx.x >> 6;        // 64 blocks per batch
    const int blk  = blockIdx.x & 63;
    const int p    = (blk << 6) + (w << 4) + qw;   // sorted position of query
    const float4* pb = ptss + (b << 12);

    const float4 qp = pb[p];
    float qs;
    {
        #pragma clang fp contract(off)
        qs = qp.x * qp.x + qp.y * qp.y + qp.z * qp.z;   // ref association order
    }

    float bd[16]; int bi[16];
    #pragma unroll
    for (int t = 0; t < 16; ++t) { bd[t] = 3.4e38f; bi[t] = 0; }

    // substream start offsets: sub0: p-0 (self), sub1: p-1, sub2: p+1, sub3: p+2
    int cp = p + ((sub == 0) ? 0 : (sub == 1) ? -1 : (sub == 2) ? 1 : 2);
    const int dcp = (sub < 2) ? -2 : 2;

    bool done = (cp < 0) || (cp >= NPTS);
    float4 c = pb[done ? p : cp];

    float pd0 = 0, pd1 = 0, pd2 = 0, pd3 = 0;
    int   pj0 = 0, pj1 = 0, pj2 = 0, pj3 = 0, cnt = 0;

    while (true) {
        const int ncp = cp + dcp;
        const int ccp = ncp < 0 ? 0 : (ncp >= NPTS ? NPTS - 1 : ncp);
        const float4 cn = pb[ccp];           // prefetch next (clamped)

        if (!done) {
            #pragma clang fp contract(off)
            const float dx  = qp.x - c.x;
            const float dxq = dx * dx;
            const float tau = bd[15];
            if (dxq > tau * 1.002f + 1e-4f) {   // conservative vs d2 cancellation noise
                done = true;
            } else {
                const float cs  = c.x * c.x + c.y * c.y + c.z * c.z;
                const float dot = qp.x * c.x + qp.y * c.y + qp.z * c.z;
                const float d2  = (qs + cs) - 2.0f * dot;   // verbatim ref formula
                const bool hit  = (d2 <= tau);  // <= : superset on exact ties, sorted out at insert
                if (hit) {
                    pd3 = pd2; pj3 = pj2; pd2 = pd1; pj2 = pj1;
                    pd1 = pd0; pj1 = pj0;
                    pd0 = d2;  pj0 = (int)__float_as_uint(c.w);
                    ++cnt;
                }
            }
        }
        if (__any(cnt >= 4)) {
            if (cnt > 3) insert16x(bd, bi, pd3, pj3);
            if (cnt > 2) insert16x(bd, bi, pd2, pj2);
            if (cnt > 1) insert16x(bd, bi, pd1, pj1);
            if (cnt > 0) insert16x(bd, bi, pd0, pj0);
            cnt = 0;
        }
        done = done || (ncp < 0) || (ncp >= NPTS);
        cp = ncp; c = cn;
        if (__all(done)) break;
    }
    if (cnt > 3) insert16x(bd, bi, pd3, pj3);
    if (cnt > 2) insert16x(bd, bi, pd2, pj2);
    if (cnt > 1) insert16x(bd, bi, pd1, pj1);
    if (cnt > 0) insert16x(bd, bi, pd0, pj0);

    // Butterfly merge across the 4 substream lanes (^32 then ^16).
    #pragma unroll
    for (int r = 32; r >= 16; r >>= 1) {
        float od[16]; int oi[16];
        #pragma unroll
        for (int t = 0; t < 16; ++t) {
            od[t] = __shfl(bd[t], lane ^ r);
            oi[t] = __shfl(bi[t], lane ^ r);
        }
        #pragma unroll
        for (int t = 0; t < 16; ++t) insert16x(bd, bi, od[t], oi[t]);
    }

    if (sub == 0) {
        const int qoi = (int)__float_as_uint(qp.w);   // original query index
        unsigned short* o = knn + ((((size_t)b << 12) + qoi) << 4);
        #pragma unroll
        for (int t = 0; t < 16; ++t) o[t] = (unsigned short)bi[t];
    }
}

// Fused gather + GEMM(bf16 MFMA) + BN + ReLU + max-over-K.
__global__ __launch_bounds__(256) void gemm_kernel(
    const short* __restrict__ xTb, const short* __restrict__ Wb,
    const unsigned short* __restrict__ knn,
    const float* __restrict__ scale, const float* __restrict__ bias,
    float* __restrict__ out)
{
    const int lane = threadIdx.x & 63;
    const int wid  = threadIdx.x >> 6;
    const int b    = blockIdx.x >> 9;            // N/8 = 512 groups per batch
    const int ng   = blockIdx.x & 511;
    const int n0   = ng * 8 + wid * 2;           // this wave's two points
    const int kl   = lane & 15;                  // A: m-index = neighbor k; B: n-index = out ch
    const int c0   = (lane >> 4) * 8;            // k-dim sub-offset within 32-chunk

    int rowoff[2];
    #pragma unroll
    for (int p = 0; p < 2; ++p) {
        const int n = n0 + p;
        const int r = (int)knn[(((size_t)b * NPTS + n) << 4) + kl];
        rowoff[p] = (b * NPTS + r) * CCH;        // element offset into xTb
    }

    const f32x4 zero = {0.f, 0.f, 0.f, 0.f};
    f32x4 acc[2][8];
    #pragma unroll
    for (int p = 0; p < 2; ++p)
        #pragma unroll
        for (int t = 0; t < 8; ++t) acc[p][t] = zero;

    #pragma unroll
    for (int kk = 0; kk < 4; ++kk) {             // K = 128 channels, 32 per MFMA
        const int cb = kk * 32 + c0;
        bf16x8 a0 = *(const bf16x8*)(xTb + rowoff[0] + cb);
        bf16x8 a1 = *(const bf16x8*)(xTb + rowoff[1] + cb);
        #pragma unroll
        for (int t = 0; t < 8; ++t) {
            const bf16x8 bf = *(const bf16x8*)(Wb + (t * 16 + kl) * CCH + cb);
            acc[0][t] = __builtin_amdgcn_mfma_f32_16x16x32_bf16(a0, bf, acc[0][t], 0, 0, 0);
            acc[1][t] = __builtin_amdgcn_mfma_f32_16x16x32_bf16(a1, bf, acc[1][t], 0, 0, 0);
        }
    }

    #pragma unroll
    for (int t = 0; t < 8; ++t) {
        const int o = t * 16 + kl;
        const float s  = scale[o];
        const float bb = bias[o];
        #pragma unroll
        for (int p = 0; p < 2; ++p) {
            const f32x4 v = acc[p][t];
            float mx = 0.f;                      // relu floor: max_k relu(y) = max(0, max_k y)
            #pragma unroll
            for (int r = 0; r < 4; ++r) mx = fmaxf(mx, v[r] * s + bb);
            mx = fmaxf(mx, __shfl_xor(mx, 16));
            mx = fmaxf(mx, __shfl_xor(mx, 32));
            if (lane < 16) out[(size_t)(b * CCH + o) * NPTS + (n0 + p)] = mx;
        }
    }
}

extern "C" void kernel_launch(void* const* d_in, const int* in_sizes, int n_in,
                              void* d_out, int out_size, void* d_ws, size_t ws_size,
                              hipStream_t stream)
{
    const float* xyz   = (const float*)d_in[0];
    const float* x     = (const float*)d_in[1];
    const float* W     = (const float*)d_in[2];
    const float* gamma = (const float*)d_in[3];
    const float* beta  = (const float*)d_in[4];
    const float* rmean = (const float*)d_in[5];
    const float* rvar  = (const float*)d_in[6];
    float* out = (float*)d_out;

    char* ws = (char*)d_ws;
    short*          xTb   = (short*)(ws);
    short*          Wb    = (short*)(ws + 8388608);
    float*          scale = (float*)(ws + 8421376);
    float*          bias  = (float*)(ws + 8421888);
    unsigned short* knn   = (unsigned short*)(ws + 8422400);
    float4*         ptss  = (float4*)(ws + 9470976);

    transpose_kernel<<<BATCH * 64 * 2, 256, 0, stream>>>(x, xTb);
    small_prep_kernel<<<CCH * CCH / 256, 256, 0, stream>>>(
        W, gamma, beta, rmean, rvar, Wb, scale, bias);
    sort_kernel<<<BATCH, 512, 0, stream>>>(xyz, ptss);
    knn_kernel<<<BATCH * 64, 256, 0, stream>>>(ptss, knn);
    gemm_kernel<<<BATCH * (NPTS / 8), 256, 0, stream>>>(xTb, Wb, knn, scale, bias, out);
}

// Round 4
// 658.884 us; speedup vs baseline: 1.7052x; 1.7052x over previous
//
#include <hip/hip_runtime.h>
#include <hip/hip_bf16.h>

// Problem constants (fixed by the reference)
#define BATCH 8
#define NPTS  4096      // N
#define CCH   128       // C
#define KNN_K 16        // K

typedef __attribute__((ext_vector_type(8))) short  bf16x8;  // 8 bf16 = 4 VGPRs
typedef __attribute__((ext_vector_type(4))) float  f32x4;   // MFMA acc

// ---------------------------------------------------------------------------
// ws layout (bytes):
//   [0)          xTb   : B*N*C bf16      = 8,388,608
//   [8388608)    Wb    : C*C  bf16       =    32,768
//   [8421376)    scale : C fp32          =       512
//   [8421888)    bias  : C fp32          =       512
//   [8422400)    pts   : B*N float4(x,y,z,s) = 524,288
//   [8946688)    knn   : B*N*K u16       = 1,048,576
// ---------------------------------------------------------------------------

static __device__ __forceinline__ short f2bf(float v) {
    __hip_bfloat16 h = __float2bfloat16(v);   // RNE
    return __builtin_bit_cast(short, h);
}

// LDS-tiled transpose: x [B,C,N] fp32 -> xTb [B,N,C] bf16.
__global__ __launch_bounds__(256) void transpose_kernel(
    const float* __restrict__ x, short* __restrict__ xTb)
{
    __shared__ short tile[64 * 66];
    const int tid = threadIdx.x;
    const int b   = blockIdx.x >> 7;         // 8 batches
    const int rem = blockIdx.x & 127;
    const int nt  = rem >> 1;                // 64 n-tiles of 64
    const int ct  = rem & 1;                 // 2 c-tiles of 64

    #pragma unroll
    for (int it = 0; it < 16; ++it) {
        const int idx = it * 256 + tid;
        const int cc  = idx >> 6;
        const int nn  = idx & 63;
        const float v = x[(size_t)(b * CCH + ct * 64 + cc) * NPTS + nt * 64 + nn];
        tile[cc * 66 + nn] = f2bf(v);
    }
    __syncthreads();
    #pragma unroll
    for (int it = 0; it < 16; ++it) {
        const int idx = it * 256 + tid;
        const int nn  = idx >> 6;
        const int cc  = idx & 63;
        xTb[(size_t)(b * NPTS + nt * 64 + nn) * CCH + ct * 64 + cc] = tile[cc * 66 + nn];
    }
}

// Small prep: W -> bf16; fold BN affine; xyz -> SoA float4 with |p|^2
__global__ __launch_bounds__(256) void small_prep_kernel(
    const float* __restrict__ xyz, const float* __restrict__ W,
    const float* __restrict__ gamma, const float* __restrict__ beta,
    const float* __restrict__ rmean, const float* __restrict__ rvar,
    short* __restrict__ Wb, float* __restrict__ scale, float* __restrict__ bias,
    float4* __restrict__ pts)
{
    const int t = blockIdx.x * 256 + threadIdx.x;   // grid covers B*N = 32768
    if (t < CCH * CCH) Wb[t] = f2bf(W[t]);
    if (t < CCH) {
        const float s = gamma[t] / sqrtf(rvar[t] + 1e-5f);
        scale[t] = s;
        bias[t]  = beta[t] - rmean[t] * s;
    }
    {
        #pragma clang fp contract(off)
        const float px = xyz[3 * t + 0];
        const float py = xyz[3 * t + 1];
        const float pz = xyz[3 * t + 2];
        const float s  = px * px + py * py + pz * pz;   // matches ref s = sum(xyz*xyz)
        pts[t] = make_float4(px, py, pz, s);
    }
}

// Streaming insert (strict <): correct for ascending-j streams (earlier j wins ties)
__device__ __forceinline__ void insert16(float bd[16], int bi[16], float d, int j) {
    #pragma unroll
    for (int t = 15; t >= 1; --t) {
        const bool ct  = d < bd[t];
        const bool ct1 = d < bd[t - 1];
        bd[t] = ct ? (ct1 ? bd[t - 1] : d) : bd[t];
        bi[t] = ct ? (ct1 ? bi[t - 1] : j) : bi[t];
    }
    if (d < bd[0]) { bd[0] = d; bi[0] = j; }
}

// Lexicographic (d, j) insert: order-independent, for cross-wave merges
__device__ __forceinline__ void insert16x(float bd[16], int bi[16], float d, int j) {
    bool lt[16];
    #pragma unroll
    for (int t = 0; t < 16; ++t) lt[t] = (d < bd[t]) || (d == bd[t] && j < bi[t]);
    #pragma unroll
    for (int t = 15; t >= 1; --t) {
        bd[t] = lt[t] ? (lt[t - 1] ? bd[t - 1] : d) : bd[t];
        bi[t] = lt[t] ? (lt[t - 1] ? bi[t - 1] : j) : bi[t];
    }
    if (lt[0]) { bd[0] = d; bi[0] = j; }
}

// Two-phase exact KNN. Block = 4 waves over the SAME 64 queries.
// Phase 1: wave w scans js [w*512, (w+1)*512) dense -> merge -> exact top-16
// of [0,2048), tau = 16th-best. Phase 2: wave w scans [2048+w*512, ...+512)
// filtered by d2 < tau (~16 expected hits per query TOTAL) -> final merge.
// Strict < + ascending j + (all phase-2 j > all phase-1 j) preserves the
// reference lowest-index tie-break exactly.
__global__ __launch_bounds__(256) void knn_kernel(
    const float4* __restrict__ pts, unsigned short* __restrict__ knn)
{
    const int lane = threadIdx.x & 63;
    const int w    = threadIdx.x >> 6;                 // 0..3
    const int b    = blockIdx.x >> 6;                  // 64 i-tiles per batch
    const int i    = ((blockIdx.x & 63) << 6) + lane;
    const float4* pb = pts + (b << 12);
    const float4 q = pb[i];

    float bd[16]; int bi[16];
    #pragma unroll
    for (int t = 0; t < 16; ++t) { bd[t] = 3.4e38f; bi[t] = 0; }

    float pd0 = 0, pd1 = 0, pd2 = 0, pd3 = 0;
    int   pj0 = 0, pj1 = 0, pj2 = 0, pj3 = 0, cnt = 0;

    // ---- Phase 1: dense scan of [w*512, (w+1)*512) ----
    {
        const int jbeg = w << 9, jend = jbeg + 512;
        for (int j = jbeg; j < jend; ++j) {
            #pragma clang fp contract(off)
            const float4 p  = pb[j];
            const float dot = q.x * p.x + q.y * p.y + q.z * p.z;
            const float d2  = (q.w + p.w) - 2.0f * dot;     // s_i + s_j - 2*dot
            const bool hit  = d2 < bd[15];
            if (__any(hit)) {
                if (hit) {
                    pd3 = pd2; pj3 = pj2; pd2 = pd1; pj2 = pj1;
                    pd1 = pd0; pj1 = pj0; pd0 = d2;  pj0 = j; ++cnt;
                }
                if (__any(cnt >= 4)) {      // oldest-first: stable ties
                    if (cnt > 3) insert16(bd, bi, pd3, pj3);
                    if (cnt > 2) insert16(bd, bi, pd2, pj2);
                    if (cnt > 1) insert16(bd, bi, pd1, pj1);
                    if (cnt > 0) insert16(bd, bi, pd0, pj0);
                    cnt = 0;
                }
            }
        }
        if (cnt > 3) insert16(bd, bi, pd3, pj3);
        if (cnt > 2) insert16(bd, bi, pd2, pj2);
        if (cnt > 1) insert16(bd, bi, pd1, pj1);
        if (cnt > 0) insert16(bd, bi, pd0, pj0);
        cnt = 0;
    }

    // ---- Merge tree (phase 1): w1->w0, w3->w2, then w2->w0 ----
    __shared__ float          sbd[2][16][64];
    __shared__ unsigned short sbi[2][16][64];
    __shared__ float          taus[64];

    if (w & 1) {
        const int s = w >> 1;
        #pragma unroll
        for (int t = 0; t < 16; ++t) { sbd[s][t][lane] = bd[t]; sbi[s][t][lane] = (unsigned short)bi[t]; }
    }
    __syncthreads();
    if (!(w & 1)) {
        const int s = w >> 1;
        #pragma unroll
        for (int t = 0; t < 16; ++t) insert16x(bd, bi, sbd[s][t][lane], (int)sbi[s][t][lane]);
    }
    __syncthreads();
    if (w == 2) {
        #pragma unroll
        for (int t = 0; t < 16; ++t) { sbd[0][t][lane] = bd[t]; sbi[0][t][lane] = (unsigned short)bi[t]; }
    }
    __syncthreads();
    if (w == 0) {
        #pragma unroll
        for (int t = 0; t < 16; ++t) insert16x(bd, bi, sbd[0][t][lane], (int)sbi[0][t][lane]);
        taus[lane] = bd[15];               // exact 16th-best of [0,2048)
    } else {
        // lists already merged into wave 0 -- reset to avoid double-counting
        #pragma unroll
        for (int t = 0; t < 16; ++t) { bd[t] = 3.4e38f; bi[t] = 0; }
    }
    __syncthreads();
    const float tau = taus[lane];

    // ---- Phase 2: filtered scan of [2048 + w*512, +512) ----
    {
        const int jbeg = 2048 + (w << 9), jend = jbeg + 512;
        for (int j = jbeg; j < jend; ++j) {
            #pragma clang fp contract(off)
            const float4 p  = pb[j];
            const float dot = q.x * p.x + q.y * p.y + q.z * p.z;
            const float d2  = (q.w + p.w) - 2.0f * dot;
            const bool hit  = (d2 < tau) && (d2 < bd[15]);
            if (__any(hit)) {
                if (hit) {
                    pd3 = pd2; pj3 = pj2; pd2 = pd1; pj2 = pj1;
                    pd1 = pd0; pj1 = pj0; pd0 = d2;  pj0 = j; ++cnt;
                }
                if (__any(cnt >= 4)) {
                    if (cnt > 3) insert16(bd, bi, pd3, pj3);
                    if (cnt > 2) insert16(bd, bi, pd2, pj2);
                    if (cnt > 1) insert16(bd, bi, pd1, pj1);
                    if (cnt > 0) insert16(bd, bi, pd0, pj0);
                    cnt = 0;
                }
            }
        }
        if (cnt > 3) insert16(bd, bi, pd3, pj3);
        if (cnt > 2) insert16(bd, bi, pd2, pj2);
        if (cnt > 1) insert16(bd, bi, pd1, pj1);
        if (cnt > 0) insert16(bd, bi, pd0, pj0);
    }
    __syncthreads();   // protect LDS reuse

    // ---- Final merge tree ----
    if (w & 1) {
        const int s = w >> 1;
        #pragma unroll
        for (int t = 0; t < 16; ++t) { sbd[s][t][lane] = bd[t]; sbi[s][t][lane] = (unsigned short)bi[t]; }
    }
    __syncthreads();
    if (!(w & 1)) {
        const int s = w >> 1;
        #pragma unroll
        for (int t = 0; t < 16; ++t) insert16x(bd, bi, sbd[s][t][lane], (int)sbi[s][t][lane]);
    }
    __syncthreads();
    if (w == 2) {
        #pragma unroll
        for (int t = 0; t < 16; ++t) { sbd[0][t][lane] = bd[t]; sbi[0][t][lane] = (unsigned short)bi[t]; }
    }
    __syncthreads();
    if (w == 0) {
        #pragma unroll
        for (int t = 0; t < 16; ++t) insert16x(bd, bi, sbd[0][t][lane], (int)sbi[0][t][lane]);
        unsigned short* o = knn + ((((size_t)b << 12) + i) << 4);
        #pragma unroll
        for (int t = 0; t < 16; ++t) o[t] = (unsigned short)bi[t];
    }
}

// Fused gather + GEMM(bf16 MFMA) + BN + ReLU + max-over-K.
__global__ __launch_bounds__(256) void gemm_kernel(
    const short* __restrict__ xTb, const short* __restrict__ Wb,
    const unsigned short* __restrict__ knn,
    const float* __restrict__ scale, const float* __restrict__ bias,
    float* __restrict__ out)
{
    const int lane = threadIdx.x & 63;
    const int wid  = threadIdx.x >> 6;
    const int b    = blockIdx.x >> 9;            // N/8 = 512 groups per batch
    const int ng   = blockIdx.x & 511;
    const int n0   = ng * 8 + wid * 2;           // this wave's two points
    const int kl   = lane & 15;                  // A: m-index = neighbor k; B: n-index = out ch
    const int c0   = (lane >> 4) * 8;            // k-dim sub-offset within 32-chunk

    int rowoff[2];
    #pragma unroll
    for (int p = 0; p < 2; ++p) {
        const int n = n0 + p;
        const int r = (int)knn[(((size_t)b * NPTS + n) << 4) + kl];
        rowoff[p] = (b * NPTS + r) * CCH;        // element offset into xTb
    }

    const f32x4 zero = {0.f, 0.f, 0.f, 0.f};
    f32x4 acc[2][8];
    #pragma unroll
    for (int p = 0; p < 2; ++p)
        #pragma unroll
        for (int t = 0; t < 8; ++t) acc[p][t] = zero;

    #pragma unroll
    for (int kk = 0; kk < 4; ++kk) {             // K = 128 channels, 32 per MFMA
        const int cb = kk * 32 + c0;
        bf16x8 a0 = *(const bf16x8*)(xTb + rowoff[0] + cb);
        bf16x8 a1 = *(const bf16x8*)(xTb + rowoff[1] + cb);
        #pragma unroll
        for (int t = 0; t < 8; ++t) {
            const bf16x8 bf = *(const bf16x8*)(Wb + (t * 16 + kl) * CCH + cb);
            acc[0][t] = __builtin_amdgcn_mfma_f32_16x16x32_bf16(a0, bf, acc[0][t], 0, 0, 0);
            acc[1][t] = __builtin_amdgcn_mfma_f32_16x16x32_bf16(a1, bf, acc[1][t], 0, 0, 0);
        }
    }

    #pragma unroll
    for (int t = 0; t < 8; ++t) {
        const int o = t * 16 + kl;
        const float s  = scale[o];
        const float bb = bias[o];
        #pragma unroll
        for (int p = 0; p < 2; ++p) {
            const f32x4 v = acc[p][t];
            float mx = 0.f;                      // relu floor: max_k relu(y) = max(0, max_k y)
            #pragma unroll
            for (int r = 0; r < 4; ++r) mx = fmaxf(mx, v[r] * s + bb);
            mx = fmaxf(mx, __shfl_xor(mx, 16));
            mx = fmaxf(mx, __shfl_xor(mx, 32));
            if (lane < 16) out[(size_t)(b * CCH + o) * NPTS + (n0 + p)] = mx;
        }
    }
}

extern "C" void kernel_launch(void* const* d_in, const int* in_sizes, int n_in,
                              void* d_out, int out_size, void* d_ws, size_t ws_size,
                              hipStream_t stream)
{
    const float* xyz   = (const float*)d_in[0];
    const float* x     = (const float*)d_in[1];
    const float* W     = (const float*)d_in[2];
    const float* gamma = (const float*)d_in[3];
    const float* beta  = (const float*)d_in[4];
    const float* rmean = (const float*)d_in[5];
    const float* rvar  = (const float*)d_in[6];
    float* out = (float*)d_out;

    char* ws = (char*)d_ws;
    short*          xTb   = (short*)(ws);
    short*          Wb    = (short*)(ws + 8388608);
    float*          scale = (float*)(ws + 8421376);
    float*          bias  = (float*)(ws + 8421888);
    float4*         pts   = (float4*)(ws + 8422400);
    unsigned short* knn   = (unsigned short*)(ws + 8946688);

    transpose_kernel<<<BATCH * 64 * 2, 256, 0, stream>>>(x, xTb);
    small_prep_kernel<<<BATCH * NPTS / 256, 256, 0, stream>>>(
        xyz, W, gamma, beta, rmean, rvar, Wb, scale, bias, pts);
    knn_kernel<<<BATCH * 64, 256, 0, stream>>>(pts, knn);
    gemm_kernel<<<BATCH * (NPTS / 8), 256, 0, stream>>>(xTb, Wb, knn, scale, bias, out);
}